// Round 9
// baseline (122.915 us; speedup 1.0000x reference)
//
#include <hip/hip_runtime.h>
#include <hip/hip_bf16.h>

#define INF_F 1e9f
#define EPS_F 1e-5f
#define QSCALE 0.1767766952966369f   // 1/sqrt(32)
#define SM_SHIFT 16.0f               // fixed softmax shift, folded into tri_bias
#define LOG2E 1.44269504088896340736f

typedef __attribute__((ext_vector_type(8))) short short8;
typedef __attribute__((ext_vector_type(4))) short bf16x4;   // HIP owns 'short4'
typedef __attribute__((ext_vector_type(4))) float f32x4;

__device__ __forceinline__ unsigned short f2bf(float f) {
    union { float f; unsigned int u; } v; v.f = f;
    return (unsigned short)((v.u + 0x8000u) >> 16);   // round-half-up
}
__device__ __forceinline__ float bf2f(unsigned short b) {
    union { unsigned int u; float f; } v; v.u = ((unsigned int)b) << 16; return v.f;
}
// pack2bf: 2 adds + 1 v_perm_b32 (bytes [2,3] of each rounded word)
__device__ __forceinline__ unsigned int pack2bf(float a, float b) {
    union { float f; unsigned int u; } ua, ub; ua.f = a; ub.f = b;
    return __builtin_amdgcn_perm(ub.u + 0x8000u, ua.u + 0x8000u, 0x07060302u);
}

#if defined(__has_builtin)
#if __has_builtin(__builtin_amdgcn_mfma_f32_16x16x16bf16_1k)
#define MFMA16BF(a, b, c) __builtin_amdgcn_mfma_f32_16x16x16bf16_1k(a, b, c, 0, 0, 0)
#endif
#endif
#ifndef MFMA16BF
__device__ __forceinline__ f32x4 mfma16bf_asm(bf16x4 a, bf16x4 b, f32x4 c) {
    asm volatile("v_mfma_f32_16x16x16_bf16 %0, %1, %2, %0\n\ts_nop 7\n\ts_nop 7"
                 : "+v"(c) : "v"(a), "v"(b));
    return c;
}
#define MFMA16BF(a, b, c) mfma16bf_asm(a, b, c)
#endif

// ---------------------------------------------------------------------------
// K0: weight prep — transpose + bf16 the 5 128x128 weights into Wt[n][k].
// Folds QSCALE*LOG2E into Wt_q (exp2-domain softmax). Order q,k,v,g,o.
// ---------------------------------------------------------------------------
__global__ __launch_bounds__(256) void prep_weights(
    const float* __restrict__ wq, const float* __restrict__ wk,
    const float* __restrict__ wv, const float* __restrict__ wg,
    const float* __restrict__ wo, unsigned short* __restrict__ wt)
{
    const int m = blockIdx.x;
    const float* W = (m == 0) ? wq : (m == 1) ? wk : (m == 2) ? wv : (m == 3) ? wg : wo;
    const float scale = (m == 0) ? QSCALE * LOG2E : 1.0f;
    unsigned short* out = wt + m * 16384;
    const int t = threadIdx.x;
    #pragma unroll
    for (int j = 0; j < 8; ++j) {
        int o = t * 64 + j * 8;
        int n = o >> 7, k0 = o & 127;
        short8 v;
        #pragma unroll
        for (int jj = 0; jj < 8; ++jj)
            v[jj] = (short)f2bf(W[(size_t)(k0 + jj) * 128 + n] * scale);
        *reinterpret_cast<short8*>(out + o) = v;
    }
}

// ---------------------------------------------------------------------------
// K1: fused LN + tri_bias + 4 projections. 128 px / 256 thr (4 waves, each
// owns 32 px = 2 m-tiles). Weights read DIRECTLY from global (L1/L2-hot,
// no LDS staging, no barriers in the y-loop). Outputs stored directly from
// accumulators (bf16 scalar stores, 4x32B bursts per inst). One barrier total.
// ---------------------------------------------------------------------------
__global__ __launch_bounds__(256) void ln_proj_kernel(
    const float* __restrict__ x, const float* __restrict__ ln_w, const float* __restrict__ ln_b,
    const float* __restrict__ w_tri, const unsigned short* __restrict__ wt,
    const float* __restrict__ b_g,
    unsigned short* __restrict__ qb, unsigned short* __restrict__ kb,
    unsigned short* __restrict__ vb, unsigned short* __restrict__ gb,
    float* __restrict__ tri_bias)
{
    __shared__ unsigned short As[128][136];  // xn bf16, 34.8 KB
    __shared__ float wt_s[512];
    __shared__ float bgs[128];

    const int tid = threadIdx.x;
    const int p0  = blockIdx.x * 128;

    if (tid < 128) bgs[tid] = b_g[tid];
    wt_s[tid] = w_tri[tid];
    wt_s[tid + 256] = w_tri[tid + 256];

    // LN: 32 threads per pixel; 128 px x 32 thr = 4096 = 16 passes of 256
    {
        const int c4 = (tid & 31) * 4;
        const float4 lw = *reinterpret_cast<const float4*>(ln_w + c4);
        const float4 lb = *reinterpret_cast<const float4*>(ln_b + c4);
        #pragma unroll
        for (int r = 0; r < 16; ++r) {
            int idx = r * 256 + tid;
            int px  = idx >> 5;
            float4 v = *reinterpret_cast<const float4*>(x + (size_t)(p0 + px) * 128 + c4);
            float s  = v.x + v.y + v.z + v.w;
            float ss = v.x * v.x + v.y * v.y + v.z * v.z + v.w * v.w;
            #pragma unroll
            for (int mk = 1; mk <= 16; mk <<= 1) {
                s  += __shfl_xor(s, mk);
                ss += __shfl_xor(ss, mk);
            }
            float mu   = s * 0.0078125f;
            float rstd = rsqrtf(ss * 0.0078125f - mu * mu + EPS_F);
            float a0 = (v.x - mu) * rstd * lw.x + lb.x;
            float a1 = (v.y - mu) * rstd * lw.y + lb.y;
            float a2 = (v.z - mu) * rstd * lw.z + lb.z;
            float a3 = (v.w - mu) * rstd * lw.w + lb.w;
            *reinterpret_cast<unsigned int*>(&As[px][c4])     = pack2bf(a0, a1);
            *reinterpret_cast<unsigned int*>(&As[px][c4 + 2]) = pack2bf(a2, a3);
        }
    }
    __syncthreads();

    // tri_bias (exp2 domain, shift folded): 128 px x 4 h = 512 = 2 passes
    #pragma unroll
    for (int r = 0; r < 2; ++r) {
        int idx = r * 256 + tid;
        int px = idx >> 2, hh = idx & 3;
        float acc = 0.f;
        #pragma unroll
        for (int kq = 0; kq < 128; kq += 8) {
            short8 xv = *reinterpret_cast<const short8*>(&As[px][kq]);
            #pragma unroll
            for (int j = 0; j < 8; ++j)
                acc = fmaf(bf2f((unsigned short)xv[j]), wt_s[(kq + j) * 4 + hh], acc);
        }
        tri_bias[hh * 65536 + p0 + px] = (acc - SM_SHIFT) * LOG2E;
    }

    const int lane = tid & 63, wid = tid >> 6;
    const int lrow = lane & 15, lgrp = lane >> 4;
    const int m0 = wid * 32;   // wave owns 32 px: m-tiles m0, m0+16

    for (int y = 0; y < 4; ++y) {
        const unsigned short* W = wt + y * 16384;
        f32x4 acc[2][8];
        #pragma unroll
        for (int mt = 0; mt < 2; ++mt)
            #pragma unroll
            for (int nt = 0; nt < 8; ++nt) acc[mt][nt] = f32x4{0.f, 0.f, 0.f, 0.f};

        #pragma unroll
        for (int kk = 0; kk < 4; ++kk) {
            short8 wf[8];
            #pragma unroll
            for (int nt = 0; nt < 8; ++nt)
                wf[nt] = *reinterpret_cast<const short8*>(
                    W + (nt * 16 + lrow) * 128 + kk * 32 + lgrp * 8);
            short8 af0 = *reinterpret_cast<const short8*>(&As[m0 + lrow][kk * 32 + lgrp * 8]);
            short8 af1 = *reinterpret_cast<const short8*>(&As[m0 + 16 + lrow][kk * 32 + lgrp * 8]);
            #pragma unroll
            for (int nt = 0; nt < 8; ++nt) {
                acc[0][nt] = __builtin_amdgcn_mfma_f32_16x16x32_bf16(af0, wf[nt], acc[0][nt], 0, 0, 0);
                acc[1][nt] = __builtin_amdgcn_mfma_f32_16x16x32_bf16(af1, wf[nt], acc[1][nt], 0, 0, 0);
            }
        }

        unsigned short* outp = (y == 0) ? qb : (y == 1) ? kb : (y == 2) ? vb : gb;
        #pragma unroll
        for (int mt = 0; mt < 2; ++mt)
            #pragma unroll
            for (int nt = 0; nt < 8; ++nt) {
                int col = nt * 16 + lrow;
                #pragma unroll
                for (int r = 0; r < 4; ++r) {
                    int row = m0 + mt * 16 + lgrp * 4 + r;
                    float vv = acc[mt][nt][r];
                    if (y == 3) vv = 1.f / (1.f + __expf(-(vv + bgs[col])));
                    outp[(size_t)(p0 + row) * 128 + col] = f2bf(vv);
                }
            }
    }
}

// ---------------------------------------------------------------------------
// K2: flash attention, swapped QK^T, exp2-domain fixed-shift softmax,
// bias+mask as MFMA C operand, software-pipelined chunk loop.
// ---------------------------------------------------------------------------
__global__ __launch_bounds__(512) void attn_kernel(
    const unsigned short* qbuf, const unsigned short* __restrict__ kbuf,
    const unsigned short* __restrict__ vbuf, const unsigned short* __restrict__ gbuf,
    const float* __restrict__ tri_bias, const float* __restrict__ mask,
    unsigned short* og)
{
    __shared__ unsigned short Ks[256][40];   // [key][c] bf16
    __shared__ unsigned short Vt[32][264];   // [c][key] bf16, XOR<<4 swizzle
    __shared__ float maskb[256];

    const int tid = threadIdx.x;
    const int i  = blockIdx.x;
    const int h  = blockIdx.y >> 1;
    const int rg = blockIdx.y & 1;
    const size_t base = (size_t)i * 32768 + (size_t)h * 32;

    #pragma unroll
    for (int r = 0; r < 2; ++r) {
        int idx = r * 512 + tid;
        int n = idx >> 2, c8 = (idx & 3) * 8;
        short8 kv = *reinterpret_cast<const short8*>(kbuf + base + (size_t)n * 128 + c8);
        short8 vv = *reinterpret_cast<const short8*>(vbuf + base + (size_t)n * 128 + c8);
        *reinterpret_cast<short8*>(&Ks[n][c8]) = kv;
        #pragma unroll
        for (int j = 0; j < 8; ++j) {
            int row = c8 + j;
            Vt[row][n ^ (((row >> 3) & 3) << 4)] = (unsigned short)vv[j];
        }
    }
    if (tid < 256) maskb[tid] = (INF_F * LOG2E) * (mask[i * 256 + tid] - 1.0f);
    __syncthreads();

    const int lane = tid & 63;
    const int wid  = tid >> 6;
    const int q    = lane & 15;
    const int g    = lane >> 4;
    const int q0   = rg * 128 + wid * 16;

    short8 qf = *reinterpret_cast<const short8*>(qbuf + base + (size_t)(q0 + q) * 128 + g * 8);

    const float* biasrow = tri_bias + (size_t)h * 65536 + (size_t)(q0 + q) * 256;
    const f32x4 z = {0.f, 0.f, 0.f, 0.f};
    f32x4 oacc[2] = {z, z};
    float lsum = 0.f;
    const int xr0 = ((q >> 3) & 1) << 4;
    const int xr1 = ((2 + (q >> 3)) & 3) << 4;

    // ---- prefetch chunk 0
    short8 kfa = *reinterpret_cast<const short8*>(&Ks[q][g * 8]);
    short8 kfb = *reinterpret_cast<const short8*>(&Ks[16 + q][g * 8]);
    f32x4 ca = *reinterpret_cast<const f32x4*>(biasrow + g * 4)
             + *reinterpret_cast<const f32x4*>(&maskb[g * 4]);
    f32x4 cb = *reinterpret_cast<const f32x4*>(biasrow + 16 + g * 4)
             + *reinterpret_cast<const f32x4*>(&maskb[16 + g * 4]);
    bf16x4 vA0 = *reinterpret_cast<const bf16x4*>(&Vt[q][(g * 4) ^ xr0]);
    bf16x4 vA1 = *reinterpret_cast<const bf16x4*>(&Vt[16 + q][(g * 4) ^ xr1]);
    bf16x4 vB0 = *reinterpret_cast<const bf16x4*>(&Vt[q][(16 + g * 4) ^ xr0]);
    bf16x4 vB1 = *reinterpret_cast<const bf16x4*>(&Vt[16 + q][(16 + g * 4) ^ xr1]);

    #pragma unroll
    for (int ch = 0; ch < 8; ++ch) {
        short8 kfa_n, kfb_n; f32x4 ca_n, cb_n;
        bf16x4 vA0_n, vA1_n, vB0_n, vB1_n;
        if (ch < 7) {
            const int nbn = (ch + 1) * 32;
            kfa_n = *reinterpret_cast<const short8*>(&Ks[nbn + q][g * 8]);
            kfb_n = *reinterpret_cast<const short8*>(&Ks[nbn + 16 + q][g * 8]);
            ca_n = *reinterpret_cast<const f32x4*>(biasrow + nbn + g * 4)
                 + *reinterpret_cast<const f32x4*>(&maskb[nbn + g * 4]);
            cb_n = *reinterpret_cast<const f32x4*>(biasrow + nbn + 16 + g * 4)
                 + *reinterpret_cast<const f32x4*>(&maskb[nbn + 16 + g * 4]);
            vA0_n = *reinterpret_cast<const bf16x4*>(&Vt[q][(nbn + g * 4) ^ xr0]);
            vA1_n = *reinterpret_cast<const bf16x4*>(&Vt[16 + q][(nbn + g * 4) ^ xr1]);
            vB0_n = *reinterpret_cast<const bf16x4*>(&Vt[q][(nbn + 16 + g * 4) ^ xr0]);
            vB1_n = *reinterpret_cast<const bf16x4*>(&Vt[16 + q][(nbn + 16 + g * 4) ^ xr1]);
        }
        // scores in exp2 domain, bias+mask pre-loaded into C
        f32x4 s0 = __builtin_amdgcn_mfma_f32_16x16x32_bf16(kfa, qf, ca, 0, 0, 0);
        f32x4 s1 = __builtin_amdgcn_mfma_f32_16x16x32_bf16(kfb, qf, cb, 0, 0, 0);
        float p00 = exp2f(s0[0]), p01 = exp2f(s0[1]);
        float p02 = exp2f(s0[2]), p03 = exp2f(s0[3]);
        float p10 = exp2f(s1[0]), p11 = exp2f(s1[1]);
        float p12 = exp2f(s1[2]), p13 = exp2f(s1[3]);
        lsum += ((p00 + p01) + (p02 + p03)) + ((p10 + p11) + (p12 + p13));
        union { unsigned int u[2]; bf16x4 s; } pA, pB;
        pA.u[0] = pack2bf(p00, p01); pA.u[1] = pack2bf(p02, p03);
        pB.u[0] = pack2bf(p10, p11); pB.u[1] = pack2bf(p12, p13);
        oacc[0] = MFMA16BF(pA.s, vA0, oacc[0]);
        oacc[1] = MFMA16BF(pA.s, vA1, oacc[1]);
        oacc[0] = MFMA16BF(pB.s, vB0, oacc[0]);
        oacc[1] = MFMA16BF(pB.s, vB1, oacc[1]);
        kfa = kfa_n; kfb = kfb_n; ca = ca_n; cb = cb_n;
        vA0 = vA0_n; vA1 = vA1_n; vB0 = vB0_n; vB1 = vB1_n;
    }

    lsum += __shfl_xor(lsum, 16);
    lsum += __shfl_xor(lsum, 32);

    float linv = 1.0f / lsum;
    #pragma unroll
    for (int r = 0; r < 4; ++r) {
        float li = __shfl(linv, g * 4 + r);
        int m = q0 + g * 4 + r;
        #pragma unroll
        for (int ct = 0; ct < 2; ++ct) {
            int c = ct * 16 + q;
            float gv = bf2f(gbuf[base + (size_t)m * 128 + c]);
            og[base + (size_t)m * 128 + c] = f2bf(oacc[ct][r] * li * gv);
        }
    }
}

// ---------------------------------------------------------------------------
// K3: output projection out = og @ w_o + b_o, 64-px blocks, f32 out.
// ---------------------------------------------------------------------------
__global__ __launch_bounds__(256) void out_proj_kernel(
    const unsigned short* __restrict__ og, const unsigned short* __restrict__ wto,
    const float* __restrict__ b_o, float* __restrict__ out)
{
    __shared__ unsigned short As[64][136];
    __shared__ unsigned short Bs[128][136];
    __shared__ float bos[128];

    const int tid = threadIdx.x;
    const int p0  = blockIdx.x * 64;
    if (tid < 128) bos[tid] = b_o[tid];

    #pragma unroll
    for (int r = 0; r < 4; ++r) {
        int idx = r * 256 + tid;
        int px = idx >> 4, k8 = (idx & 15) * 8;
        *reinterpret_cast<short8*>(&As[px][k8]) =
            *reinterpret_cast<const short8*>(og + (size_t)(p0 + px) * 128 + k8);
    }
    #pragma unroll
    for (int r = 0; r < 8; ++r) {
        int idx = r * 256 + tid;
        int n = idx >> 4, k8 = (idx & 15) * 8;
        *reinterpret_cast<short8*>(&Bs[n][k8]) =
            *reinterpret_cast<const short8*>(wto + n * 128 + k8);
    }
    __syncthreads();

    const int lane = tid & 63, wid = tid >> 6;
    const int lrow = lane & 15, lgrp = lane >> 4;
    const int m0 = wid * 16;

    f32x4 acc[8];
    #pragma unroll
    for (int nt = 0; nt < 8; ++nt) acc[nt] = f32x4{0.f, 0.f, 0.f, 0.f};

    #pragma unroll
    for (int kk = 0; kk < 4; ++kk) {
        short8 af = *reinterpret_cast<const short8*>(&As[m0 + lrow][kk * 32 + lgrp * 8]);
        short8 bfr[8];
        #pragma unroll
        for (int nt = 0; nt < 8; ++nt)
            bfr[nt] = *reinterpret_cast<const short8*>(&Bs[nt * 16 + lrow][kk * 32 + lgrp * 8]);
        #pragma unroll
        for (int nt = 0; nt < 8; ++nt)
            acc[nt] = __builtin_amdgcn_mfma_f32_16x16x32_bf16(af, bfr[nt], acc[nt], 0, 0, 0);
    }

    #pragma unroll
    for (int nt = 0; nt < 8; ++nt)
        #pragma unroll
        for (int r = 0; r < 4; ++r) {
            int row = m0 + lgrp * 4 + r;
            int col = nt * 16 + lrow;
            out[(size_t)(p0 + row) * 128 + col] = acc[nt][r] + bos[col];
        }
}

extern "C" void kernel_launch(void* const* d_in, const int* in_sizes, int n_in,
                              void* d_out, int out_size, void* d_ws, size_t ws_size,
                              hipStream_t stream)
{
    const float* x     = (const float*)d_in[0];
    const float* mask  = (const float*)d_in[1];
    const float* ln_w  = (const float*)d_in[2];
    const float* ln_b  = (const float*)d_in[3];
    const float* w_tri = (const float*)d_in[4];
    const float* w_q   = (const float*)d_in[5];
    const float* w_k   = (const float*)d_in[6];
    const float* w_v   = (const float*)d_in[7];
    const float* w_g   = (const float*)d_in[8];
    const float* b_g   = (const float*)d_in[9];
    const float* w_o   = (const float*)d_in[10];
    const float* b_o   = (const float*)d_in[11];
    float* out = (float*)d_out;

    // ws: q(=og) | k | v | g (bf16) | tri_bias f32 | Wt bf16
    unsigned short* qb = (unsigned short*)d_ws;
    unsigned short* kb = qb + 8388608;
    unsigned short* vb = kb + 8388608;
    unsigned short* gb = vb + 8388608;
    float* bias = (float*)(gb + 8388608);
    unsigned short* wt = (unsigned short*)(bias + 4 * 65536);

    prep_weights<<<dim3(5), 256, 0, stream>>>(w_q, w_k, w_v, w_g, w_o, wt);
    ln_proj_kernel<<<512, 256, 0, stream>>>(
        x, ln_w, ln_b, w_tri, wt, b_g, qb, kb, vb, gb, bias);
    attn_kernel<<<dim3(256, 8), 512, 0, stream>>>(
        qb, kb, vb, gb, bias, mask, qb /*og aliases q: disjoint slices, read-before-write*/);
    out_proj_kernel<<<1024, 256, 0, stream>>>(qb, wt + 4 * 16384, b_o, out);
}

// Round 10
// 96.054 us; speedup vs baseline: 1.2796x; 1.2796x over previous
//
#include <hip/hip_runtime.h>
#include <hip/hip_bf16.h>

#define INF_F 1e9f
#define EPS_F 1e-5f
#define QSCALE 0.1767766952966369f   // 1/sqrt(32)
#define SM_SHIFT 16.0f               // fixed softmax shift, folded into tri_bias
#define LOG2E 1.44269504088896340736f

typedef __attribute__((ext_vector_type(8))) short short8;
typedef __attribute__((ext_vector_type(4))) short bf16x4;   // HIP owns 'short4'
typedef __attribute__((ext_vector_type(4))) float f32x4;

__device__ __forceinline__ unsigned short f2bf(float f) {
    union { float f; unsigned int u; } v; v.f = f;
    return (unsigned short)((v.u + 0x8000u) >> 16);   // round-half-up
}
__device__ __forceinline__ float bf2f(unsigned short b) {
    union { unsigned int u; float f; } v; v.u = ((unsigned int)b) << 16; return v.f;
}
// pack2bf: 2 adds + 1 v_perm_b32 (bytes [2,3] of each rounded word)
__device__ __forceinline__ unsigned int pack2bf(float a, float b) {
    union { float f; unsigned int u; } ua, ub; ua.f = a; ub.f = b;
    return __builtin_amdgcn_perm(ub.u + 0x8000u, ua.u + 0x8000u, 0x07060302u);
}

#if defined(__has_builtin)
#if __has_builtin(__builtin_amdgcn_mfma_f32_16x16x16bf16_1k)
#define MFMA16BF(a, b, c) __builtin_amdgcn_mfma_f32_16x16x16bf16_1k(a, b, c, 0, 0, 0)
#endif
#endif
#ifndef MFMA16BF
__device__ __forceinline__ f32x4 mfma16bf_asm(bf16x4 a, bf16x4 b, f32x4 c) {
    asm volatile("v_mfma_f32_16x16x16_bf16 %0, %1, %2, %0\n\ts_nop 7\n\ts_nop 7"
                 : "+v"(c) : "v"(a), "v"(b));
    return c;
}
#define MFMA16BF(a, b, c) mfma16bf_asm(a, b, c)
#endif

// ---------------------------------------------------------------------------
// K0: weight prep — transpose + bf16 the 5 128x128 weights into Wt[n][k].
// Folds QSCALE*LOG2E into Wt_q (exp2-domain softmax). Order q,k,v,g,o.
// ---------------------------------------------------------------------------
__global__ __launch_bounds__(256) void prep_weights(
    const float* __restrict__ wq, const float* __restrict__ wk,
    const float* __restrict__ wv, const float* __restrict__ wg,
    const float* __restrict__ wo, unsigned short* __restrict__ wt)
{
    const int m = blockIdx.x;
    const float* W = (m == 0) ? wq : (m == 1) ? wk : (m == 2) ? wv : (m == 3) ? wg : wo;
    const float scale = (m == 0) ? QSCALE * LOG2E : 1.0f;
    unsigned short* out = wt + m * 16384;
    const int t = threadIdx.x;
    #pragma unroll
    for (int j = 0; j < 8; ++j) {
        int o = t * 64 + j * 8;
        int n = o >> 7, k0 = o & 127;
        short8 v;
        #pragma unroll
        for (int jj = 0; jj < 8; ++jj)
            v[jj] = (short)f2bf(W[(size_t)(k0 + jj) * 128 + n] * scale);
        *reinterpret_cast<short8*>(out + o) = v;
    }
}

// ---------------------------------------------------------------------------
// K1 v3: fused LN + tri_bias + 4 projections. 128 px / 512 thr (8 waves,
// wave owns 16 px x 128 cols). A-fragments hoisted to registers (y-invariant)
// so the xn LDS buffer is ALIASED by the weight staging buffer (35 KB total).
// Next-y weights register-prefetched under current-y MFMAs. Direct stores
// from accumulators. 2 barriers per y (8 total).
// ---------------------------------------------------------------------------
__global__ __launch_bounds__(512, 4) void ln_proj_kernel(
    const float* __restrict__ x, const float* __restrict__ ln_w, const float* __restrict__ ln_b,
    const float* __restrict__ w_tri, const unsigned short* __restrict__ wt,
    const float* __restrict__ b_g,
    unsigned short* __restrict__ qb, unsigned short* __restrict__ kb,
    unsigned short* __restrict__ vb, unsigned short* __restrict__ gb,
    float* __restrict__ tri_bias)
{
    __shared__ unsigned short smem[128 * 136];   // phase1: xn (As); y-loop: W (Bs)
    __shared__ float wt_s[512];
    __shared__ float bgs[128];
    unsigned short (*As)[136] = reinterpret_cast<unsigned short(*)[136]>(smem);
    unsigned short (*Bs)[136] = reinterpret_cast<unsigned short(*)[136]>(smem);

    const int tid = threadIdx.x;
    const int p0  = blockIdx.x * 128;

    if (tid < 128) bgs[tid] = b_g[tid];
    if (tid < 512) wt_s[tid] = w_tri[tid & 511];

    // ---- phase 1: LN -> As (bf16). 128 px x 32 thr = 4096 = 8 passes of 512.
    {
        const int c4 = (tid & 31) * 4;
        const float4 lw = *reinterpret_cast<const float4*>(ln_w + c4);
        const float4 lb = *reinterpret_cast<const float4*>(ln_b + c4);
        #pragma unroll
        for (int r = 0; r < 8; ++r) {
            int idx = r * 512 + tid;
            int px  = idx >> 5;
            float4 v = *reinterpret_cast<const float4*>(x + (size_t)(p0 + px) * 128 + c4);
            float s  = v.x + v.y + v.z + v.w;
            float ss = v.x * v.x + v.y * v.y + v.z * v.z + v.w * v.w;
            #pragma unroll
            for (int mk = 1; mk <= 16; mk <<= 1) {
                s  += __shfl_xor(s, mk);
                ss += __shfl_xor(ss, mk);
            }
            float mu   = s * 0.0078125f;
            float rstd = rsqrtf(ss * 0.0078125f - mu * mu + EPS_F);
            float a0 = (v.x - mu) * rstd * lw.x + lb.x;
            float a1 = (v.y - mu) * rstd * lw.y + lb.y;
            float a2 = (v.z - mu) * rstd * lw.z + lb.z;
            float a3 = (v.w - mu) * rstd * lw.w + lb.w;
            *reinterpret_cast<unsigned int*>(&As[px][c4])     = pack2bf(a0, a1);
            *reinterpret_cast<unsigned int*>(&As[px][c4 + 2]) = pack2bf(a2, a3);
        }
    }
    __syncthreads();

    // tri_bias (exp2 domain, shift folded): 128 px x 4 h = 512, one pass
    {
        const int px = tid >> 2, hh = tid & 3;
        float acc = 0.f;
        #pragma unroll
        for (int kq = 0; kq < 128; kq += 8) {
            short8 xv = *reinterpret_cast<const short8*>(&As[px][kq]);
            #pragma unroll
            for (int j = 0; j < 8; ++j)
                acc = fmaf(bf2f((unsigned short)xv[j]), wt_s[(kq + j) * 4 + hh], acc);
        }
        tri_bias[hh * 65536 + p0 + px] = (acc - SM_SHIFT) * LOG2E;
    }

    const int lane = tid & 63, wid = tid >> 6;
    const int lrow = lane & 15, lgrp = lane >> 4;
    const int m0 = wid * 16;   // wave owns 16 px

    // ---- hoist A-fragments (y-invariant) to registers
    short8 af[4];
    #pragma unroll
    for (int kk = 0; kk < 4; ++kk)
        af[kk] = *reinterpret_cast<const short8*>(&As[m0 + lrow][kk * 32 + lgrp * 8]);

    // ---- prefetch W[0] into registers (64 B / thread)
    short8 wreg[4];
    #pragma unroll
    for (int p = 0; p < 4; ++p)
        wreg[p] = *reinterpret_cast<const short8*>(wt + (p * 512 + tid) * 8);

    __syncthreads();   // all As readers (tri, af) done before Bs overwrites

    for (int y = 0; y < 4; ++y) {
        // commit staged W to LDS (aliases As)
        #pragma unroll
        for (int p = 0; p < 4; ++p) {
            int idx = p * 512 + tid;
            *reinterpret_cast<short8*>(&Bs[idx >> 4][(idx & 15) * 8]) = wreg[p];
        }
        __syncthreads();

        // issue next y's weight loads (land during MFMAs)
        if (y < 3) {
            const unsigned short* Wn = wt + (y + 1) * 16384;
            #pragma unroll
            for (int p = 0; p < 4; ++p)
                wreg[p] = *reinterpret_cast<const short8*>(Wn + (p * 512 + tid) * 8);
        }

        f32x4 acc[8];
        #pragma unroll
        for (int nt = 0; nt < 8; ++nt) acc[nt] = f32x4{0.f, 0.f, 0.f, 0.f};
        #pragma unroll
        for (int kk = 0; kk < 4; ++kk) {
            short8 wf[8];
            #pragma unroll
            for (int nt = 0; nt < 8; ++nt)
                wf[nt] = *reinterpret_cast<const short8*>(&Bs[nt * 16 + lrow][kk * 32 + lgrp * 8]);
            #pragma unroll
            for (int nt = 0; nt < 8; ++nt)
                acc[nt] = __builtin_amdgcn_mfma_f32_16x16x32_bf16(af[kk], wf[nt], acc[nt], 0, 0, 0);
        }

        // epilogue: transform + direct store from accumulators
        unsigned short* outp = (y == 0) ? qb : (y == 1) ? kb : (y == 2) ? vb : gb;
        #pragma unroll
        for (int nt = 0; nt < 8; ++nt) {
            int col = nt * 16 + lrow;
            #pragma unroll
            for (int r = 0; r < 4; ++r) {
                int row = m0 + lgrp * 4 + r;
                float vv = acc[nt][r];
                if (y == 3) vv = 1.f / (1.f + __expf(-(vv + bgs[col])));
                outp[(size_t)(p0 + row) * 128 + col] = f2bf(vv);
            }
        }
        __syncthreads();   // Bs readers done before next y's writes
    }
}

// ---------------------------------------------------------------------------
// K2: flash attention, swapped QK^T, exp2-domain fixed-shift softmax,
// bias+mask as MFMA C operand, software-pipelined chunk loop.
// ---------------------------------------------------------------------------
__global__ __launch_bounds__(512) void attn_kernel(
    const unsigned short* qbuf, const unsigned short* __restrict__ kbuf,
    const unsigned short* __restrict__ vbuf, const unsigned short* __restrict__ gbuf,
    const float* __restrict__ tri_bias, const float* __restrict__ mask,
    unsigned short* og)
{
    __shared__ unsigned short Ks[256][40];   // [key][c] bf16
    __shared__ unsigned short Vt[32][264];   // [c][key] bf16, XOR<<4 swizzle
    __shared__ float maskb[256];

    const int tid = threadIdx.x;
    const int i  = blockIdx.x;
    const int h  = blockIdx.y >> 1;
    const int rg = blockIdx.y & 1;
    const size_t base = (size_t)i * 32768 + (size_t)h * 32;

    #pragma unroll
    for (int r = 0; r < 2; ++r) {
        int idx = r * 512 + tid;
        int n = idx >> 2, c8 = (idx & 3) * 8;
        short8 kv = *reinterpret_cast<const short8*>(kbuf + base + (size_t)n * 128 + c8);
        short8 vv = *reinterpret_cast<const short8*>(vbuf + base + (size_t)n * 128 + c8);
        *reinterpret_cast<short8*>(&Ks[n][c8]) = kv;
        #pragma unroll
        for (int j = 0; j < 8; ++j) {
            int row = c8 + j;
            Vt[row][n ^ (((row >> 3) & 3) << 4)] = (unsigned short)vv[j];
        }
    }
    if (tid < 256) maskb[tid] = (INF_F * LOG2E) * (mask[i * 256 + tid] - 1.0f);
    __syncthreads();

    const int lane = tid & 63;
    const int wid  = tid >> 6;
    const int q    = lane & 15;
    const int g    = lane >> 4;
    const int q0   = rg * 128 + wid * 16;

    short8 qf = *reinterpret_cast<const short8*>(qbuf + base + (size_t)(q0 + q) * 128 + g * 8);

    const float* biasrow = tri_bias + (size_t)h * 65536 + (size_t)(q0 + q) * 256;
    const f32x4 z = {0.f, 0.f, 0.f, 0.f};
    f32x4 oacc[2] = {z, z};
    float lsum = 0.f;
    const int xr0 = ((q >> 3) & 1) << 4;
    const int xr1 = ((2 + (q >> 3)) & 3) << 4;

    // ---- prefetch chunk 0
    short8 kfa = *reinterpret_cast<const short8*>(&Ks[q][g * 8]);
    short8 kfb = *reinterpret_cast<const short8*>(&Ks[16 + q][g * 8]);
    f32x4 ca = *reinterpret_cast<const f32x4*>(biasrow + g * 4)
             + *reinterpret_cast<const f32x4*>(&maskb[g * 4]);
    f32x4 cb = *reinterpret_cast<const f32x4*>(biasrow + 16 + g * 4)
             + *reinterpret_cast<const f32x4*>(&maskb[16 + g * 4]);
    bf16x4 vA0 = *reinterpret_cast<const bf16x4*>(&Vt[q][(g * 4) ^ xr0]);
    bf16x4 vA1 = *reinterpret_cast<const bf16x4*>(&Vt[16 + q][(g * 4) ^ xr1]);
    bf16x4 vB0 = *reinterpret_cast<const bf16x4*>(&Vt[q][(16 + g * 4) ^ xr0]);
    bf16x4 vB1 = *reinterpret_cast<const bf16x4*>(&Vt[16 + q][(16 + g * 4) ^ xr1]);

    #pragma unroll
    for (int ch = 0; ch < 8; ++ch) {
        short8 kfa_n, kfb_n; f32x4 ca_n, cb_n;
        bf16x4 vA0_n, vA1_n, vB0_n, vB1_n;
        if (ch < 7) {
            const int nbn = (ch + 1) * 32;
            kfa_n = *reinterpret_cast<const short8*>(&Ks[nbn + q][g * 8]);
            kfb_n = *reinterpret_cast<const short8*>(&Ks[nbn + 16 + q][g * 8]);
            ca_n = *reinterpret_cast<const f32x4*>(biasrow + nbn + g * 4)
                 + *reinterpret_cast<const f32x4*>(&maskb[nbn + g * 4]);
            cb_n = *reinterpret_cast<const f32x4*>(biasrow + nbn + 16 + g * 4)
                 + *reinterpret_cast<const f32x4*>(&maskb[nbn + 16 + g * 4]);
            vA0_n = *reinterpret_cast<const bf16x4*>(&Vt[q][(nbn + g * 4) ^ xr0]);
            vA1_n = *reinterpret_cast<const bf16x4*>(&Vt[16 + q][(nbn + g * 4) ^ xr1]);
            vB0_n = *reinterpret_cast<const bf16x4*>(&Vt[q][(nbn + 16 + g * 4) ^ xr0]);
            vB1_n = *reinterpret_cast<const bf16x4*>(&Vt[16 + q][(nbn + 16 + g * 4) ^ xr1]);
        }
        // scores in exp2 domain, bias+mask pre-loaded into C
        f32x4 s0 = __builtin_amdgcn_mfma_f32_16x16x32_bf16(kfa, qf, ca, 0, 0, 0);
        f32x4 s1 = __builtin_amdgcn_mfma_f32_16x16x32_bf16(kfb, qf, cb, 0, 0, 0);
        float p00 = exp2f(s0[0]), p01 = exp2f(s0[1]);
        float p02 = exp2f(s0[2]), p03 = exp2f(s0[3]);
        float p10 = exp2f(s1[0]), p11 = exp2f(s1[1]);
        float p12 = exp2f(s1[2]), p13 = exp2f(s1[3]);
        lsum += ((p00 + p01) + (p02 + p03)) + ((p10 + p11) + (p12 + p13));
        union { unsigned int u[2]; bf16x4 s; } pA, pB;
        pA.u[0] = pack2bf(p00, p01); pA.u[1] = pack2bf(p02, p03);
        pB.u[0] = pack2bf(p10, p11); pB.u[1] = pack2bf(p12, p13);
        oacc[0] = MFMA16BF(pA.s, vA0, oacc[0]);
        oacc[1] = MFMA16BF(pA.s, vA1, oacc[1]);
        oacc[0] = MFMA16BF(pB.s, vB0, oacc[0]);
        oacc[1] = MFMA16BF(pB.s, vB1, oacc[1]);
        kfa = kfa_n; kfb = kfb_n; ca = ca_n; cb = cb_n;
        vA0 = vA0_n; vA1 = vA1_n; vB0 = vB0_n; vB1 = vB1_n;
    }

    lsum += __shfl_xor(lsum, 16);
    lsum += __shfl_xor(lsum, 32);

    float linv = 1.0f / lsum;
    #pragma unroll
    for (int r = 0; r < 4; ++r) {
        float li = __shfl(linv, g * 4 + r);
        int m = q0 + g * 4 + r;
        #pragma unroll
        for (int ct = 0; ct < 2; ++ct) {
            int c = ct * 16 + q;
            float gv = bf2f(gbuf[base + (size_t)m * 128 + c]);
            og[base + (size_t)m * 128 + c] = f2bf(oacc[ct][r] * li * gv);
        }
    }
}

// ---------------------------------------------------------------------------
// K3: output projection out = og @ w_o + b_o, 64-px blocks, f32 out.
// ---------------------------------------------------------------------------
__global__ __launch_bounds__(256) void out_proj_kernel(
    const unsigned short* __restrict__ og, const unsigned short* __restrict__ wto,
    const float* __restrict__ b_o, float* __restrict__ out)
{
    __shared__ unsigned short As[64][136];
    __shared__ unsigned short Bs[128][136];
    __shared__ float bos[128];

    const int tid = threadIdx.x;
    const int p0  = blockIdx.x * 64;
    if (tid < 128) bos[tid] = b_o[tid];

    #pragma unroll
    for (int r = 0; r < 4; ++r) {
        int idx = r * 256 + tid;
        int px = idx >> 4, k8 = (idx & 15) * 8;
        *reinterpret_cast<short8*>(&As[px][k8]) =
            *reinterpret_cast<const short8*>(og + (size_t)(p0 + px) * 128 + k8);
    }
    #pragma unroll
    for (int r = 0; r < 8; ++r) {
        int idx = r * 256 + tid;
        int n = idx >> 4, k8 = (idx & 15) * 8;
        *reinterpret_cast<short8*>(&Bs[n][k8]) =
            *reinterpret_cast<const short8*>(wto + n * 128 + k8);
    }
    __syncthreads();

    const int lane = tid & 63, wid = tid >> 6;
    const int lrow = lane & 15, lgrp = lane >> 4;
    const int m0 = wid * 16;

    f32x4 acc[8];
    #pragma unroll
    for (int nt = 0; nt < 8; ++nt) acc[nt] = f32x4{0.f, 0.f, 0.f, 0.f};

    #pragma unroll
    for (int kk = 0; kk < 4; ++kk) {
        short8 af = *reinterpret_cast<const short8*>(&As[m0 + lrow][kk * 32 + lgrp * 8]);
        short8 bfr[8];
        #pragma unroll
        for (int nt = 0; nt < 8; ++nt)
            bfr[nt] = *reinterpret_cast<const short8*>(&Bs[nt * 16 + lrow][kk * 32 + lgrp * 8]);
        #pragma unroll
        for (int nt = 0; nt < 8; ++nt)
            acc[nt] = __builtin_amdgcn_mfma_f32_16x16x32_bf16(af, bfr[nt], acc[nt], 0, 0, 0);
    }

    #pragma unroll
    for (int nt = 0; nt < 8; ++nt)
        #pragma unroll
        for (int r = 0; r < 4; ++r) {
            int row = m0 + lgrp * 4 + r;
            int col = nt * 16 + lrow;
            out[(size_t)(p0 + row) * 128 + col] = acc[nt][r] + bos[col];
        }
}

extern "C" void kernel_launch(void* const* d_in, const int* in_sizes, int n_in,
                              void* d_out, int out_size, void* d_ws, size_t ws_size,
                              hipStream_t stream)
{
    const float* x     = (const float*)d_in[0];
    const float* mask  = (const float*)d_in[1];
    const float* ln_w  = (const float*)d_in[2];
    const float* ln_b  = (const float*)d_in[3];
    const float* w_tri = (const float*)d_in[4];
    const float* w_q   = (const float*)d_in[5];
    const float* w_k   = (const float*)d_in[6];
    const float* w_v   = (const float*)d_in[7];
    const float* w_g   = (const float*)d_in[8];
    const float* b_g   = (const float*)d_in[9];
    const float* w_o   = (const float*)d_in[10];
    const float* b_o   = (const float*)d_in[11];
    float* out = (float*)d_out;

    // ws: q(=og) | k | v | g (bf16) | tri_bias f32 | Wt bf16
    unsigned short* qb = (unsigned short*)d_ws;
    unsigned short* kb = qb + 8388608;
    unsigned short* vb = kb + 8388608;
    unsigned short* gb = vb + 8388608;
    float* bias = (float*)(gb + 8388608);
    unsigned short* wt = (unsigned short*)(bias + 4 * 65536);

    prep_weights<<<dim3(5), 256, 0, stream>>>(w_q, w_k, w_v, w_g, w_o, wt);
    ln_proj_kernel<<<512, 512, 0, stream>>>(
        x, ln_w, ln_b, w_tri, wt, b_g, qb, kb, vb, gb, bias);
    attn_kernel<<<dim3(256, 8), 512, 0, stream>>>(
        qb, kb, vb, gb, bias, mask, qb /*og aliases q: disjoint slices, read-before-write*/);
    out_proj_kernel<<<1024, 256, 0, stream>>>(qb, wt + 4 * 16384, b_o, out);
}